// Round 17
// baseline (30.913 us; speedup 1.0000x reference)
//
#include <hip/hip_runtime.h>
#include <math.h>

#define NN 20
#define ED 4
#define XROW 160
#define NC 80
#define NKT 5
#define NNT 5
#define FRAG_BYTES (NKT * NNT * 64 * 16)     // 25600
#define THREADS 512
#define ROWS_PER_WAVE 16
#define ROWS_PER_BLOCK 128                   // 8 waves * 16 rows
#define TPB 2                                // tiles per persistent block

typedef __attribute__((ext_vector_type(8))) _Float16 half8;
typedef __attribute__((ext_vector_type(4))) float f32x4;
typedef __attribute__((ext_vector_type(4))) unsigned uint4v;

static __device__ __forceinline__ half8 cvt8(float4 a, float4 b) {
    uint4v u = (uint4v){
        __builtin_bit_cast(unsigned, __builtin_amdgcn_cvt_pkrtz(a.x, a.y)),
        __builtin_bit_cast(unsigned, __builtin_amdgcn_cvt_pkrtz(a.z, a.w)),
        __builtin_bit_cast(unsigned, __builtin_amdgcn_cvt_pkrtz(b.x, b.y)),
        __builtin_bit_cast(unsigned, __builtin_amdgcn_cvt_pkrtz(b.z, b.w))};
    return __builtin_bit_cast(half8, u);
}

// quad_perm DPP: xor1 = [1,0,3,2] = 0xB1 ; xor2 = [2,3,0,1] = 0x4E
static __device__ __forceinline__ float dpp_xor1(float v) {
    return __builtin_bit_cast(float,
        __builtin_amdgcn_mov_dpp(__builtin_bit_cast(int, v), 0xB1, 0xF, 0xF, true));
}
static __device__ __forceinline__ float dpp_xor2(float v) {
    return __builtin_bit_cast(float,
        __builtin_amdgcn_mov_dpp(__builtin_bit_cast(int, v), 0x4E, 0xF, 0xF, true));
}

struct Burst {
    float4 a0, b0, a1, b1, a2, b2, a3, b3, a4, b4;
};

static __device__ __forceinline__ Burst load_burst(const float* __restrict__ p) {
    Burst r;
    r.a0 = *(const float4*)(p);       r.b0 = *(const float4*)(p + 4);
    r.a1 = *(const float4*)(p + 32);  r.b1 = *(const float4*)(p + 36);
    r.a2 = *(const float4*)(p + 64);  r.b2 = *(const float4*)(p + 68);
    r.a3 = *(const float4*)(p + 96);  r.b3 = *(const float4*)(p + 100);
    r.a4 = *(const float4*)(p + 128); r.b4 = *(const float4*)(p + 132);
    return r;
}

__global__ __launch_bounds__(THREADS, 4) void rgcn_fused(
        const float* __restrict__ x,
        const float* __restrict__ e,
        const float* __restrict__ gate_w,
        const float* __restrict__ gate_b,
        const float* __restrict__ upd_w,
        const float* __restrict__ upd_b,
        const float* __restrict__ lin_w,
        const float* __restrict__ lin_b,
        float* __restrict__ y) {
    __shared__ __align__(16) char fragmem[FRAG_BYTES];
    __shared__ float sbias[NC];
    __shared__ float el[80];
    __shared__ float sA[400];
    __shared__ float wself[640];
    __shared__ float wagg[640];

    const int t = threadIdx.x;
    const int l = t & 63;
    const int w = t >> 6;

    const size_t rowA = ((size_t)blockIdx.x * TPB + 0) * ROWS_PER_BLOCK + (size_t)w * ROWS_PER_WAVE;
    const size_t rowB = ((size_t)blockIdx.x * TPB + 1) * ROWS_PER_BLOCK + (size_t)w * ROWS_PER_WAVE;
    const float* xpA = x + (rowA + (l & 15)) * XROW + ((l >> 4) << 3);
    const float* xpB = x + (rowB + (l & 15)) * XROW + ((l >> 4) << 3);

    // ---- burst A: issued first, latency hidden under setup ----
    Burst bA = load_burst(xpA);

    // ---- setup (once per block, amortized over 2 tiles) ----
    if (t < NN * ED) el[t] = e[t];
    __syncthreads();

    if (t < 400) {
        int nn = t / 20, mm = t - (t / 20) * 20;
        float d = 0.f;
        #pragma unroll
        for (int j = 0; j < ED; ++j) d += el[nn * ED + j] * el[mm * ED + j];
        sA[t] = fmaxf(d, 0.f);
    }
    #pragma unroll
    for (int idx = t; idx < 1280; idx += THREADS) {
        int sel = idx >= 640;
        int rem = sel ? idx - 640 : idx;
        int c = rem >> 3, i = rem & 7;
        int n = c >> 2, ro = c & 3;
        float v = 0.f;
        if (ro < 2) {
            int o = 2 + ro;
            #pragma unroll
            for (int d = 0; d < ED; ++d) v += el[n * ED + d] * gate_w[d * 80 + sel * 40 + i * 4 + o];
        } else {
            int o = ro - 2;
            #pragma unroll
            for (int d = 0; d < ED; ++d) v += el[n * ED + d] * upd_w[d * 40 + sel * 20 + i * 2 + o];
        }
        (sel ? wagg : wself)[rem] = v;
    }
    if (t < NC) {
        int n = t >> 2, ro = t & 3;
        float b = 0.f;
        #pragma unroll
        for (int d = 0; d < ED; ++d)
            b += el[n * ED + d] * (ro < 2 ? gate_b[d * 4 + 2 + ro] : upd_b[d * 2 + ro - 2]);
        sbias[t] = b;
    }
    __syncthreads();

    if (t < NN) {
        float mx = -1e30f;
        for (int m = 0; m < NN; ++m) mx = fmaxf(mx, sA[t * 20 + m]);
        float ex[NN]; float sum = 0.f;
        for (int m = 0; m < NN; ++m) { ex[m] = __expf(sA[t * 20 + m] - mx); sum += ex[m]; }
        float inv = 1.f / sum;
        for (int m = 0; m < NN; ++m) sA[t * 20 + m] = ex[m] * inv;
    }
    __syncthreads();

    {
        half8* frag = (half8*)fragmem;
        for (int tile = w; tile < NKT * NNT; tile += 8) {
            int kt = tile / 5, nt = tile - kt * 5;
            int cc = nt * 16 + (l & 15);
            int nn = cc >> 2;
            int mm = kt * 4 + (l >> 4);
            float anm = sA[nn * 20 + mm];
            float4 wg0 = *(const float4*)&wagg[cc * 8];
            float4 wg1 = *(const float4*)&wagg[cc * 8 + 4];
            float v0 = anm * wg0.x, v1 = anm * wg0.y, v2 = anm * wg0.z, v3 = anm * wg0.w;
            float v4 = anm * wg1.x, v5 = anm * wg1.y, v6 = anm * wg1.z, v7 = anm * wg1.w;
            if (nn == mm) {
                float4 ws0 = *(const float4*)&wself[cc * 8];
                float4 ws1 = *(const float4*)&wself[cc * 8 + 4];
                v0 += ws0.x; v1 += ws0.y; v2 += ws0.z; v3 += ws0.w;
                v4 += ws1.x; v5 += ws1.y; v6 += ws1.z; v7 += ws1.w;
            }
            half8 hv;
            hv[0] = (_Float16)v0; hv[1] = (_Float16)v1; hv[2] = (_Float16)v2; hv[3] = (_Float16)v3;
            hv[4] = (_Float16)v4; hv[5] = (_Float16)v5; hv[6] = (_Float16)v6; hv[7] = (_Float16)v7;
            frag[tile * 64 + l] = hv;
        }
    }
    __syncthreads();

    const half8* frag = (const half8*)fragmem;
    const float lw0 = lin_w[0], lw1 = lin_w[1], lb = lin_b[0];
    const int ro = l & 3;
    const bool isR = ro < 2;
    const float myw = (ro & 1) ? lw1 : lw0;

    // ---- burst B issued NOW: latency hides under tile A's MFMA+epilogue ----
    Burst bB = load_burst(xpB);

    #define STEP(XA, XB, KT, ACC)                                                   \
    {                                                                               \
        half8 a = cvt8(XA, XB);                                                     \
        _Pragma("unroll")                                                           \
        for (int nt = 0; nt < NNT; ++nt) {                                          \
            half8 bh = frag[((KT) * NNT + nt) * 64 + l];                            \
            ACC[nt] = __builtin_amdgcn_mfma_f32_16x16x32_f16(a, bh, ACC[nt], 0, 0, 0); \
        }                                                                           \
    }

    #define EPILOGUE(ACC, ROW0)                                                     \
    {                                                                               \
        const size_t rowb = (ROW0) + ((l >> 4) << 2) + ro;                          \
        _Pragma("unroll")                                                           \
        for (int nt = 0; nt < NNT; ++nt) {                                          \
            const int n = nt * 4 + ((l & 15) >> 2);                                 \
            float ysel = 0.f;                                                       \
            _Pragma("unroll")                                                       \
            for (int q = 0; q < 4; ++q) {                                           \
                float pre = ACC[nt][q];                                             \
                float term;                                                         \
                if (isR) term = __builtin_amdgcn_rcpf(1.f + __expf(pre));           \
                else     term = 1.f - 2.f * __builtin_amdgcn_rcpf(__expf(2.f * pre) + 1.f); \
                float other = dpp_xor2(term);                                       \
                float h = term * other;                                             \
                float s = fmaxf(h, 0.f) * myw;                                      \
                float yq = s + dpp_xor1(s) + lb;                                    \
                if (q == ro) ysel = yq;                                             \
            }                                                                       \
            __builtin_nontemporal_store(ysel, &y[rowb * NN + n]);                   \
        }                                                                           \
    }

    // ---- tile A ----
    {
        f32x4 accA[NNT];
        #pragma unroll
        for (int nt = 0; nt < NNT; ++nt) {
            float b = sbias[nt * 16 + (l & 15)];
            accA[nt] = (f32x4){b, b, b, b};
        }
        STEP(bA.a0, bA.b0, 0, accA)
        STEP(bA.a1, bA.b1, 1, accA)
        STEP(bA.a2, bA.b2, 2, accA)
        STEP(bA.a3, bA.b3, 3, accA)
        STEP(bA.a4, bA.b4, 4, accA)
        EPILOGUE(accA, rowA)
    }

    // ---- tile B ----
    {
        f32x4 accB[NNT];
        #pragma unroll
        for (int nt = 0; nt < NNT; ++nt) {
            float b = sbias[nt * 16 + (l & 15)];
            accB[nt] = (f32x4){b, b, b, b};
        }
        STEP(bB.a0, bB.b0, 0, accB)
        STEP(bB.a1, bB.b1, 1, accB)
        STEP(bB.a2, bB.b2, 2, accB)
        STEP(bB.a3, bB.b3, 3, accB)
        STEP(bB.a4, bB.b4, 4, accB)
        EPILOGUE(accB, rowB)
    }
    #undef STEP
    #undef EPILOGUE
}

extern "C" void kernel_launch(void* const* d_in, const int* in_sizes, int n_in,
                              void* d_out, int out_size, void* d_ws, size_t ws_size,
                              hipStream_t stream) {
    const float* x      = (const float*)d_in[0];
    const float* e      = (const float*)d_in[1];
    const float* gate_w = (const float*)d_in[2];
    const float* gate_b = (const float*)d_in[3];
    const float* upd_w  = (const float*)d_in[4];
    const float* upd_b  = (const float*)d_in[5];
    const float* lin_w  = (const float*)d_in[6];
    const float* lin_b  = (const float*)d_in[7];
    float* y = (float*)d_out;

    const int Bn = in_sizes[0] / XROW;                     // 131072
    const int nblocks = Bn / (ROWS_PER_BLOCK * TPB);       // 512

    rgcn_fused<<<nblocks, THREADS, 0, stream>>>(x, e, gate_w, gate_b,
                                                upd_w, upd_b, lin_w, lin_b, y);
}

// Round 18
// 24.640 us; speedup vs baseline: 1.2546x; 1.2546x over previous
//
#include <hip/hip_runtime.h>
#include <math.h>

#define NN 20
#define ED 4
#define XROW 160
#define NC 80
#define NKT 5
#define NNT 5
#define FRAG_BYTES (NKT * NNT * 64 * 16)     // 25600
#define THREADS 512
#define ROWS_PER_WAVE 16
#define ROWS_PER_BLOCK 128                   // 8 waves * 16 rows
#define TPB 2                                // tiles per persistent block

typedef __attribute__((ext_vector_type(8))) _Float16 half8;
typedef __attribute__((ext_vector_type(4))) float f32x4;
typedef __attribute__((ext_vector_type(4))) unsigned uint4v;

static __device__ __forceinline__ half8 cvt8(float4 a, float4 b) {
    uint4v u = (uint4v){
        __builtin_bit_cast(unsigned, __builtin_amdgcn_cvt_pkrtz(a.x, a.y)),
        __builtin_bit_cast(unsigned, __builtin_amdgcn_cvt_pkrtz(a.z, a.w)),
        __builtin_bit_cast(unsigned, __builtin_amdgcn_cvt_pkrtz(b.x, b.y)),
        __builtin_bit_cast(unsigned, __builtin_amdgcn_cvt_pkrtz(b.z, b.w))};
    return __builtin_bit_cast(half8, u);
}

// quad_perm DPP: xor1 = [1,0,3,2] = 0xB1 ; xor2 = [2,3,0,1] = 0x4E
static __device__ __forceinline__ float dpp_xor1(float v) {
    return __builtin_bit_cast(float,
        __builtin_amdgcn_mov_dpp(__builtin_bit_cast(int, v), 0xB1, 0xF, 0xF, true));
}
static __device__ __forceinline__ float dpp_xor2(float v) {
    return __builtin_bit_cast(float,
        __builtin_amdgcn_mov_dpp(__builtin_bit_cast(int, v), 0x4E, 0xF, 0xF, true));
}

struct Burst {
    float4 a0, b0, a1, b1, a2, b2, a3, b3, a4, b4;
};

static __device__ __forceinline__ Burst load_burst(const float* __restrict__ p) {
    Burst r;
    r.a0 = *(const float4*)(p);       r.b0 = *(const float4*)(p + 4);
    r.a1 = *(const float4*)(p + 32);  r.b1 = *(const float4*)(p + 36);
    r.a2 = *(const float4*)(p + 64);  r.b2 = *(const float4*)(p + 68);
    r.a3 = *(const float4*)(p + 96);  r.b3 = *(const float4*)(p + 100);
    r.a4 = *(const float4*)(p + 128); r.b4 = *(const float4*)(p + 132);
    return r;
}

__global__ __launch_bounds__(THREADS, 4) void rgcn_fused(
        const float* __restrict__ x,
        const float* __restrict__ e,
        const float* __restrict__ gate_w,
        const float* __restrict__ gate_b,
        const float* __restrict__ upd_w,
        const float* __restrict__ upd_b,
        const float* __restrict__ lin_w,
        const float* __restrict__ lin_b,
        float* __restrict__ y) {
    __shared__ __align__(16) char fragmem[FRAG_BYTES];
    __shared__ float sbias[NC];
    __shared__ float el[80];
    __shared__ float sA[400];
    __shared__ float wself[640];
    __shared__ float wagg[640];

    const int t = threadIdx.x;
    const int l = t & 63;
    const int w = t >> 6;

    // rows for this wave's two tiles
    const size_t rowA = ((size_t)blockIdx.x * TPB + 0) * ROWS_PER_BLOCK + (size_t)w * ROWS_PER_WAVE;
    const size_t rowB = ((size_t)blockIdx.x * TPB + 1) * ROWS_PER_BLOCK + (size_t)w * ROWS_PER_WAVE;
    const float* xpA = x + (rowA + (l & 15)) * XROW + ((l >> 4) << 3);
    const float* xpB = x + (rowB + (l & 15)) * XROW + ((l >> 4) << 3);

    // ---- burst A: issued first, latency hidden under setup ----
    Burst bA = load_burst(xpA);

    // ---- setup (once per block, amortized over 2 tiles) ----
    if (t < NN * ED) el[t] = e[t];
    __syncthreads();

    if (t < 400) {
        int nn = t / 20, mm = t - (t / 20) * 20;
        float d = 0.f;
        #pragma unroll
        for (int j = 0; j < ED; ++j) d += el[nn * ED + j] * el[mm * ED + j];
        sA[t] = fmaxf(d, 0.f);
    }
    #pragma unroll
    for (int idx = t; idx < 1280; idx += THREADS) {
        int sel = idx >= 640;
        int rem = sel ? idx - 640 : idx;
        int c = rem >> 3, i = rem & 7;
        int n = c >> 2, ro = c & 3;
        float v = 0.f;
        if (ro < 2) {
            int o = 2 + ro;
            #pragma unroll
            for (int d = 0; d < ED; ++d) v += el[n * ED + d] * gate_w[d * 80 + sel * 40 + i * 4 + o];
        } else {
            int o = ro - 2;
            #pragma unroll
            for (int d = 0; d < ED; ++d) v += el[n * ED + d] * upd_w[d * 40 + sel * 20 + i * 2 + o];
        }
        (sel ? wagg : wself)[rem] = v;
    }
    if (t < NC) {
        int n = t >> 2, ro = t & 3;
        float b = 0.f;
        #pragma unroll
        for (int d = 0; d < ED; ++d)
            b += el[n * ED + d] * (ro < 2 ? gate_b[d * 4 + 2 + ro] : upd_b[d * 2 + ro - 2]);
        sbias[t] = b;
    }
    __syncthreads();

    if (t < NN) {
        float mx = -1e30f;
        for (int m = 0; m < NN; ++m) mx = fmaxf(mx, sA[t * 20 + m]);
        float ex[NN]; float sum = 0.f;
        for (int m = 0; m < NN; ++m) { ex[m] = __expf(sA[t * 20 + m] - mx); sum += ex[m]; }
        float inv = 1.f / sum;
        for (int m = 0; m < NN; ++m) sA[t * 20 + m] = ex[m] * inv;
    }
    __syncthreads();

    {
        half8* frag = (half8*)fragmem;
        for (int tile = w; tile < NKT * NNT; tile += 8) {
            int kt = tile / 5, nt = tile - kt * 5;
            int cc = nt * 16 + (l & 15);
            int nn = cc >> 2;
            int mm = kt * 4 + (l >> 4);
            float anm = sA[nn * 20 + mm];
            float4 wg0 = *(const float4*)&wagg[cc * 8];
            float4 wg1 = *(const float4*)&wagg[cc * 8 + 4];
            float v0 = anm * wg0.x, v1 = anm * wg0.y, v2 = anm * wg0.z, v3 = anm * wg0.w;
            float v4 = anm * wg1.x, v5 = anm * wg1.y, v6 = anm * wg1.z, v7 = anm * wg1.w;
            if (nn == mm) {
                float4 ws0 = *(const float4*)&wself[cc * 8];
                float4 ws1 = *(const float4*)&wself[cc * 8 + 4];
                v0 += ws0.x; v1 += ws0.y; v2 += ws0.z; v3 += ws0.w;
                v4 += ws1.x; v5 += ws1.y; v6 += ws1.z; v7 += ws1.w;
            }
            half8 hv;
            hv[0] = (_Float16)v0; hv[1] = (_Float16)v1; hv[2] = (_Float16)v2; hv[3] = (_Float16)v3;
            hv[4] = (_Float16)v4; hv[5] = (_Float16)v5; hv[6] = (_Float16)v6; hv[7] = (_Float16)v7;
            frag[tile * 64 + l] = hv;
        }
    }
    __syncthreads();

    const half8* frag = (const half8*)fragmem;
    const float lw0 = lin_w[0], lw1 = lin_w[1], lb = lin_b[0];
    const int ro = l & 3;
    const bool isR = ro < 2;
    const float myw = (ro & 1) ? lw1 : lw0;

    // ---- burst B issued NOW: latency hides under tile A's MFMA+epilogue ----
    Burst bB = load_burst(xpB);

    #define STEP(XA, XB, KT, ACC)                                                   \
    {                                                                               \
        half8 a = cvt8(XA, XB);                                                     \
        _Pragma("unroll")                                                           \
        for (int nt = 0; nt < NNT; ++nt) {                                          \
            half8 bh = frag[((KT) * NNT + nt) * 64 + l];                            \
            ACC[nt] = __builtin_amdgcn_mfma_f32_16x16x32_f16(a, bh, ACC[nt], 0, 0, 0); \
        }                                                                           \
    }

    #define EPILOGUE(ACC, ROW0)                                                     \
    {                                                                               \
        const size_t rowb = (ROW0) + ((l >> 4) << 2) + ro;                          \
        _Pragma("unroll")                                                           \
        for (int nt = 0; nt < NNT; ++nt) {                                          \
            const int n = nt * 4 + ((l & 15) >> 2);                                 \
            float ysel = 0.f;                                                       \
            _Pragma("unroll")                                                       \
            for (int q = 0; q < 4; ++q) {                                           \
                float pre = ACC[nt][q];                                             \
                float term;                                                         \
                if (isR) term = __builtin_amdgcn_rcpf(1.f + __expf(pre));           \
                else     term = 1.f - 2.f * __builtin_amdgcn_rcpf(__expf(2.f * pre) + 1.f); \
                float other = dpp_xor2(term);                                       \
                float h = term * other;                                             \
                float s = fmaxf(h, 0.f) * myw;                                      \
                float yq = s + dpp_xor1(s) + lb;                                    \
                if (q == ro) ysel = yq;                                             \
            }                                                                       \
            y[rowb * NN + n] = ysel;                                                \
        }                                                                           \
    }

    // ---- tile A ----
    {
        f32x4 accA[NNT];
        #pragma unroll
        for (int nt = 0; nt < NNT; ++nt) {
            float b = sbias[nt * 16 + (l & 15)];
            accA[nt] = (f32x4){b, b, b, b};
        }
        STEP(bA.a0, bA.b0, 0, accA)
        STEP(bA.a1, bA.b1, 1, accA)
        STEP(bA.a2, bA.b2, 2, accA)
        STEP(bA.a3, bA.b3, 3, accA)
        STEP(bA.a4, bA.b4, 4, accA)
        EPILOGUE(accA, rowA)
    }

    // ---- tile B ----
    {
        f32x4 accB[NNT];
        #pragma unroll
        for (int nt = 0; nt < NNT; ++nt) {
            float b = sbias[nt * 16 + (l & 15)];
            accB[nt] = (f32x4){b, b, b, b};
        }
        STEP(bB.a0, bB.b0, 0, accB)
        STEP(bB.a1, bB.b1, 1, accB)
        STEP(bB.a2, bB.b2, 2, accB)
        STEP(bB.a3, bB.b3, 3, accB)
        STEP(bB.a4, bB.b4, 4, accB)
        EPILOGUE(accB, rowB)
    }
    #undef STEP
    #undef EPILOGUE
}

extern "C" void kernel_launch(void* const* d_in, const int* in_sizes, int n_in,
                              void* d_out, int out_size, void* d_ws, size_t ws_size,
                              hipStream_t stream) {
    const float* x      = (const float*)d_in[0];
    const float* e      = (const float*)d_in[1];
    const float* gate_w = (const float*)d_in[2];
    const float* gate_b = (const float*)d_in[3];
    const float* upd_w  = (const float*)d_in[4];
    const float* upd_b  = (const float*)d_in[5];
    const float* lin_w  = (const float*)d_in[6];
    const float* lin_b  = (const float*)d_in[7];
    float* y = (float*)d_out;

    const int Bn = in_sizes[0] / XROW;                     // 131072
    const int nblocks = Bn / (ROWS_PER_BLOCK * TPB);       // 512

    rgcn_fused<<<nblocks, THREADS, 0, stream>>>(x, e, gate_w, gate_b,
                                                upd_w, upd_b, lin_w, lin_b, y);
}